// Round 12
// baseline (335.848 us; speedup 1.0000x reference)
//
#include <hip/hip_runtime.h>
#include <hip/hip_bf16.h>

// FeatureAlign deformable 3x3 conv, G=4, PAD=1.
// R12 = R11 with BK=128 (2 gk per K-iteration): halves barrier count (36->18)
// and doubles in-flight loads per wave (8 A-frag + 8 corner). All L2 line
// traffic is already at the f16 minimum (weights/corners/output 100% line
// utilization; fp8 fails the error budget: ~0.045 > 0.039 threshold), so the
// remaining gap (57% of L2 ceiling) is attacked via fewer syncs + deeper
// natural pipelining. sB = 2 buf x 2 tiles (32 KB); LDS 71.8 KB/block.

#define Bn   8
#define CIN  256
#define COUT 256
#define Hn   64
#define Wn   64
#define Gn   4
#define Kn   9
#define CPG  64
#define GK   36
#define NP   18              // gk pairs

typedef _Float16 f16x8 __attribute__((ext_vector_type(8)));
typedef _Float16 f16x2 __attribute__((ext_vector_type(2)));
typedef float    f32x16 __attribute__((ext_vector_type(16)));

// LDS-only barrier: wait for DS ops, do NOT drain vmcnt.
#define BAR_LDS() asm volatile("s_waitcnt lgkmcnt(0)\n\ts_barrier" ::: "memory")

static __device__ __forceinline__ f16x2 pair_of(const f16x8& v, int r) {
    int4 u = __builtin_bit_cast(int4, v);
    int  p = (r == 0) ? u.x : (r == 1) ? u.y : (r == 2) ? u.z : u.w;
    return __builtin_bit_cast(f16x2, p);
}

// ---------------------------------------------------------------------------
// Fused prep (unchanged from R10/R11).
//  blocks [0, 4096):        x (b,c,y,x) f32 -> xt (b, y*64+x, c) f16 [NHWC]
//  blocks [4096, 4096+32):  w_deform -> fragment-linear f16 wfrag
//    wfrag[((gk*8 + mt8)*4 + ks4)*512 + lane*8 + j]
//    o = mt8*32 + (lane&31), c = ks4*16 + (lane>>5)*8 + j.
// ---------------------------------------------------------------------------
#define SWPAD 578
__global__ void fa_prep(const float* __restrict__ x, const float* __restrict__ w,
                        _Float16* __restrict__ xt, _Float16* __restrict__ wfrag) {
    const int bid = blockIdx.x, t = threadIdx.x;
    __shared__ _Float16 sw[32 * SWPAD];
    if (bid < 4096) {
        const int c8q = bid & 7, hwt = (bid >> 3) & 63, b = bid >> 9;
        const int hw = hwt * 64 + (t & 63);
        const int c8 = c8q * 4 + (t >> 6);
        const float* xp = x + ((size_t)(b * CIN + c8 * 8) << 12) + hw;
        f16x8 v;
#pragma unroll
        for (int j = 0; j < 8; j++) v[j] = (_Float16)xp[(size_t)j << 12];
        *(f16x8*)&xt[(((size_t)b << 12) + hw) * 256 + c8 * 8] = v;
    } else {
        const int bid2 = bid - 4096;
        const int mt8 = bid2 >> 2, g = bid2 & 3;
        const int r = t >> 3, tr = t & 7;
        const float* wp = w + (size_t)(mt8 * 32 + r) * (CIN * Kn) + g * (CPG * Kn);
#pragma unroll
        for (int it = 0; it < 18; it++) {
            int off = it * 32 + tr * 4;
            float4 v = *(const float4*)(wp + off);
            _Float16* d = &sw[r * SWPAD + off];
            d[0] = (_Float16)v.x; d[1] = (_Float16)v.y;
            d[2] = (_Float16)v.z; d[3] = (_Float16)v.w;
        }
        __syncthreads();
#pragma unroll
        for (int it = 0; it < 9; it++) {
            int chunk = it * 256 + t;
            int lane = chunk & 63, ks4 = (chunk >> 6) & 3, k9 = chunk >> 8;
            int gk = g * Kn + k9;
            int ol = lane & 31;
            int cbase = ks4 * 16 + (lane >> 5) * 8;
            f16x8 v;
#pragma unroll
            for (int j = 0; j < 8; j++)
                v[j] = sw[ol * SWPAD + (cbase + j) * Kn + k9];
            *(f16x8*)&wfrag[(((size_t)gk * 8 + mt8) * 4 + ks4) * 512 + lane * 8] = v;
        }
    }
}

// ---------------------------------------------------------------------------
// Main: 512 blocks x 512 threads. Block = bp*128 + h*2 + wh.
// N = 64 (2 b x 32 w); M = 256 over 8 waves (32 o-rows, 32x32 MFMA).
// K-loop over 18 gk-PAIRS (BK=128).
// ---------------------------------------------------------------------------
__global__ __launch_bounds__(512, 4)
void fa_main(const _Float16* __restrict__ xt, const float* __restrict__ shp,
             const float* __restrict__ w_off, const _Float16* __restrict__ wfrag,
             float* __restrict__ out) {
    const int blk = blockIdx.x;
    const int bp = blk >> 7, h = (blk >> 1) & 63, wh = blk & 1;
    const int w0 = wh * 32;
    const int t = threadIdx.x;
    const int wid = t >> 6, lane = t & 63;
    const int l31 = lane & 31, lhi = lane >> 5;
    const int cg = t & 7, nl = (t >> 3) & 63;

    __shared__ __align__(16) int4 s_meta[GK * 64];          // 36864 B
    __shared__ __align__(16) _Float16 sB[2][2][64 * 64];    // 32768 B
    __shared__ float s_shp[2 * 4 * 32];                     //  1024 B
    __shared__ float s_woff[GK * 8];                        //  1152 B

    // ---- stage shp slice + all 288 w_off ----
    if (t < 256) {
        int bb = t >> 7, c = (t >> 5) & 3, wl = t & 31;
        s_shp[t] = shp[(((bp * 2 + bb) * 4 + c) << 12) + h * Wn + w0 + wl];
    }
    for (int u = t; u < GK * 8; u += 512) s_woff[u] = w_off[u];
    __syncthreads();

    // ---- meta: one 16B record per (gk, n): {lin01, lin23, alpha f16x4} ----
    for (int i = t; i < GK * 64; i += 512) {
        int gk = i >> 6, n = i & 63;
        int bb = n >> 5, wl = n & 31;
        int g = gk / Kn, k = gk - g * Kn;
        int ky = k / 3, kx = k - ky * 3;
        float dy = 0.f, dx = 0.f;
#pragma unroll
        for (int c = 0; c < 4; c++) {
            float sv = s_shp[(bb * 4 + c) * 32 + wl];
            dy = fmaf(s_woff[gk * 8 + c],     sv, dy);
            dx = fmaf(s_woff[gk * 8 + 4 + c], sv, dx);
        }
        float py = (float)(h + ky - 1) + dy;
        float px = (float)(w0 + wl + kx - 1) + dx;
        float y0 = floorf(py), x0 = floorf(px);
        float fy = py - y0, fx = px - x0;
        int iy = (int)y0, ix = (int)x0;
        bool y0v = (unsigned)iy       < (unsigned)Hn;
        bool y1v = (unsigned)(iy + 1) < (unsigned)Hn;
        bool x0v = (unsigned)ix       < (unsigned)Wn;
        bool x1v = (unsigned)(ix + 1) < (unsigned)Wn;
        int yc0 = min(max(iy, 0), Hn - 1), yc1 = min(max(iy + 1, 0), Hn - 1);
        int xc0 = min(max(ix, 0), Wn - 1), xc1 = min(max(ix + 1, 0), Wn - 1);
        int l00 = yc0 * Wn + xc0, l01 = yc0 * Wn + xc1;
        int l10 = yc1 * Wn + xc0, l11 = yc1 * Wn + xc1;
        float wy1 = fy, wy0 = 1.f - fy, wx1 = fx, wx0 = 1.f - fx;
        float w00 = (y0v && x0v) ? wy0 * wx0 : 0.f;
        float w01 = (y0v && x1v) ? wy0 * wx1 : 0.f;
        float w10 = (y1v && x0v) ? wy1 * wx0 : 0.f;
        float w11 = (y1v && x1v) ? wy1 * wx1 : 0.f;
        f16x2 p0, p1;
        p0.x = (_Float16)w00; p0.y = (_Float16)w01;
        p1.x = (_Float16)w10; p1.y = (_Float16)w11;
        s_meta[i] = make_int4(l00 | (l01 << 16), l10 | (l11 << 16),
                              __builtin_bit_cast(int, p0),
                              __builtin_bit_cast(int, p1));
    }

    // two corner-register slots (gk pairs in flight)
    f16x8 c4[2][2][4];          // [slot][gk-in-pair][corner]
    int2  amv[2][2];

    auto issue = [&](int p, int slot) {     // corners for gk pair p
#pragma unroll
        for (int g2 = 0; g2 < 2; g2++) {
            int gk = p * 2 + g2;
            int4 mv = s_meta[gk * 64 + nl];
            amv[slot][g2].x = mv.z; amv[slot][g2].y = mv.w;
            int b = bp * 2 + (nl >> 5);
            int g = gk / Kn;
            const _Float16* base = xt + (((size_t)b << 12)) * 256 + g * CPG + cg * 8;
            c4[slot][g2][0] = *(const f16x8*)(base + (size_t)(mv.x & 0xffff) * 256);
            c4[slot][g2][1] = *(const f16x8*)(base + (size_t)((unsigned)mv.x >> 16) * 256);
            c4[slot][g2][2] = *(const f16x8*)(base + (size_t)(mv.y & 0xffff) * 256);
            c4[slot][g2][3] = *(const f16x8*)(base + (size_t)((unsigned)mv.y >> 16) * 256);
        }
    };
    auto commit = [&](int slot, int buf) {  // interp both tiles -> sB[buf]
#pragma unroll
        for (int g2 = 0; g2 < 2; g2++) {
            f16x2 h0 = __builtin_bit_cast(f16x2, amv[slot][g2].x);
            f16x2 h1 = __builtin_bit_cast(f16x2, amv[slot][g2].y);
            f16x2 a00; a00.x = h0.x; a00.y = h0.x;
            f16x2 a01; a01.x = h0.y; a01.y = h0.y;
            f16x2 a10; a10.x = h1.x; a10.y = h1.x;
            f16x2 a11; a11.x = h1.y; a11.y = h1.y;
            int4 rp;
#pragma unroll
            for (int r = 0; r < 4; r++) {
                f16x2 s = a00 * pair_of(c4[slot][g2][0], r);
                s = a01 * pair_of(c4[slot][g2][1], r) + s;
                s = a10 * pair_of(c4[slot][g2][2], r) + s;
                s = a11 * pair_of(c4[slot][g2][3], r) + s;
                int sv = __builtin_bit_cast(int, s);
                if (r == 0) rp.x = sv; else if (r == 1) rp.y = sv;
                else if (r == 2) rp.z = sv; else rp.w = sv;
            }
            *(int4*)&sB[buf][g2][(nl * 8 + (cg ^ (nl & 7))) * 8] = rp;
        }
    };

    f32x16 acc[2];
#pragma unroll
    for (int nt = 0; nt < 2; nt++)
#pragma unroll
        for (int r = 0; r < 16; r++) acc[nt][r] = 0.f;

    __syncthreads();            // meta visible

    issue(0, 0);
    commit(0, 0);               // sB[0] = tiles of pair 0
    issue(1, 1);                // corners(pair 1) in slot 1
    BAR_LDS();

    for (int p = 0; p < NP; p++) {
        const int buf = p & 1;
        // 1) A-frags for THIS pair (8 loads)
        f16x8 af[8];
#pragma unroll
        for (int g2 = 0; g2 < 2; g2++) {
            const _Float16* wbase = wfrag + (((size_t)(p * 2 + g2) * 8 + wid) * 4) * 512;
#pragma unroll
            for (int ks = 0; ks < 4; ks++)
                af[g2 * 4 + ks] = *(const f16x8*)(wbase + ((size_t)ks * 64 + lane) * 8);
        }
        // 2) interp pair p+1 (corners landed last iter) -> other buffer
        if (p + 1 < NP) commit((p + 1) & 1, buf ^ 1);
        // 3) corner loads for pair p+2 into the freed slot
        if (p + 2 < NP) issue(p + 2, p & 1);
        // 4) MFMA on buf: 8 K-steps (2 tiles x 4 ks) x 2 n-tiles
#pragma unroll
        for (int ks8 = 0; ks8 < 8; ks8++) {
            int tile = ks8 >> 2;
            int cb = (ks8 & 3) * 2 + lhi;
#pragma unroll
            for (int nt = 0; nt < 2; nt++) {
                int n = nt * 32 + l31;
                f16x8 bf = *(const f16x8*)&sB[buf][tile][(n * 8 + (cb ^ (n & 7))) * 8];
                acc[nt] = __builtin_amdgcn_mfma_f32_32x32x16_f16(
                    af[ks8], bf, acc[nt], 0, 0, 0);
            }
        }
        BAR_LDS();              // LDS-only barrier: no vmcnt drain
    }

    // ---- epilogue: C/D 32x32: col=lane&31, row=(reg&3)+8*(reg>>2)+4*lhi ----
#pragma unroll
    for (int nt = 0; nt < 2; nt++) {
        int b = bp * 2 + nt;
        float* op = out + ((size_t)b * COUT << 12) + h * Wn + w0 + l31;
#pragma unroll
        for (int reg = 0; reg < 16; reg++) {
            int row = (reg & 3) + 8 * (reg >> 2) + 4 * lhi;
            int o = wid * 32 + row;
            op[(size_t)o << 12] = fmaxf(acc[nt][reg], 0.f);
        }
    }
}

// ---------------------------------------------------------------------------
extern "C" void kernel_launch(void* const* d_in, const int* in_sizes, int n_in,
                              void* d_out, int out_size, void* d_ws, size_t ws_size,
                              hipStream_t stream) {
    const float* x     = (const float*)d_in[0];
    const float* shp   = (const float*)d_in[1];
    const float* w_off = (const float*)d_in[2];
    const float* w_def = (const float*)d_in[3];
    float* out = (float*)d_out;
    _Float16* wfrag = (_Float16*)d_ws;                         // 1.18 MB
    _Float16* xt    = (_Float16*)((char*)d_ws + (2u << 20));   // 16.8 MB

    fa_prep<<<4096 + 32, 256, 0, stream>>>(x, w_def, xt, wfrag);
    fa_main<<<512, 512, 0, stream>>>(xt, shp, w_off, wfrag, out);
}

// Round 13
// 147.215 us; speedup vs baseline: 2.2813x; 2.2813x over previous
//
#include <hip/hip_runtime.h>
#include <hip/hip_bf16.h>

// FeatureAlign deformable 3x3 conv, G=4, PAD=1.
// R13 = BK=128 (2 gk per K-iteration, 18 barriers) done WITHOUT R12's fatal
// flaw: R12 indexed the corner register array by a runtime slot (p&1) ->
// compiler demoted it to scratch (WRITE_SIZE 696 MB, 252 us). Here the
// R11 single-slot pipeline is lifted to pair granularity -- commit(pair p+1)
// then issue(pair p+2) reuse ONE c4[2][4] array with fully-unrolled
// (compile-time) indices. VGPR ~115 < 128 cap at 4 waves/SIMD.

#define Bn   8
#define CIN  256
#define COUT 256
#define Hn   64
#define Wn   64
#define Gn   4
#define Kn   9
#define CPG  64
#define GK   36
#define NP   18              // gk pairs

typedef _Float16 f16x8 __attribute__((ext_vector_type(8)));
typedef _Float16 f16x2 __attribute__((ext_vector_type(2)));
typedef float    f32x16 __attribute__((ext_vector_type(16)));

// LDS-only barrier: wait for DS ops, do NOT drain vmcnt.
#define BAR_LDS() asm volatile("s_waitcnt lgkmcnt(0)\n\ts_barrier" ::: "memory")

static __device__ __forceinline__ f16x2 pair_of(const f16x8& v, int r) {
    int4 u = __builtin_bit_cast(int4, v);
    int  p = (r == 0) ? u.x : (r == 1) ? u.y : (r == 2) ? u.z : u.w;
    return __builtin_bit_cast(f16x2, p);
}

// ---------------------------------------------------------------------------
// Fused prep (unchanged from R10/R11).
//  blocks [0, 4096):        x (b,c,y,x) f32 -> xt (b, y*64+x, c) f16 [NHWC]
//  blocks [4096, 4096+32):  w_deform -> fragment-linear f16 wfrag
//    wfrag[((gk*8 + mt8)*4 + ks4)*512 + lane*8 + j]
//    o = mt8*32 + (lane&31), c = ks4*16 + (lane>>5)*8 + j.
// ---------------------------------------------------------------------------
#define SWPAD 578
__global__ void fa_prep(const float* __restrict__ x, const float* __restrict__ w,
                        _Float16* __restrict__ xt, _Float16* __restrict__ wfrag) {
    const int bid = blockIdx.x, t = threadIdx.x;
    __shared__ _Float16 sw[32 * SWPAD];
    if (bid < 4096) {
        const int c8q = bid & 7, hwt = (bid >> 3) & 63, b = bid >> 9;
        const int hw = hwt * 64 + (t & 63);
        const int c8 = c8q * 4 + (t >> 6);
        const float* xp = x + ((size_t)(b * CIN + c8 * 8) << 12) + hw;
        f16x8 v;
#pragma unroll
        for (int j = 0; j < 8; j++) v[j] = (_Float16)xp[(size_t)j << 12];
        *(f16x8*)&xt[(((size_t)b << 12) + hw) * 256 + c8 * 8] = v;
    } else {
        const int bid2 = bid - 4096;
        const int mt8 = bid2 >> 2, g = bid2 & 3;
        const int r = t >> 3, tr = t & 7;
        const float* wp = w + (size_t)(mt8 * 32 + r) * (CIN * Kn) + g * (CPG * Kn);
#pragma unroll
        for (int it = 0; it < 18; it++) {
            int off = it * 32 + tr * 4;
            float4 v = *(const float4*)(wp + off);
            _Float16* d = &sw[r * SWPAD + off];
            d[0] = (_Float16)v.x; d[1] = (_Float16)v.y;
            d[2] = (_Float16)v.z; d[3] = (_Float16)v.w;
        }
        __syncthreads();
#pragma unroll
        for (int it = 0; it < 9; it++) {
            int chunk = it * 256 + t;
            int lane = chunk & 63, ks4 = (chunk >> 6) & 3, k9 = chunk >> 8;
            int gk = g * Kn + k9;
            int ol = lane & 31;
            int cbase = ks4 * 16 + (lane >> 5) * 8;
            f16x8 v;
#pragma unroll
            for (int j = 0; j < 8; j++)
                v[j] = sw[ol * SWPAD + (cbase + j) * Kn + k9];
            *(f16x8*)&wfrag[(((size_t)gk * 8 + mt8) * 4 + ks4) * 512 + lane * 8] = v;
        }
    }
}

// ---------------------------------------------------------------------------
// Main: 512 blocks x 512 threads. Block = bp*128 + h*2 + wh.
// N = 64 (2 b x 32 w); M = 256 over 8 waves (32 o-rows, 32x32 MFMA).
// K-loop over 18 gk-PAIRS (BK=128), 1 barrier per pair.
// ---------------------------------------------------------------------------
__global__ __launch_bounds__(512, 4)
void fa_main(const _Float16* __restrict__ xt, const float* __restrict__ shp,
             const float* __restrict__ w_off, const _Float16* __restrict__ wfrag,
             float* __restrict__ out) {
    const int blk = blockIdx.x;
    const int bp = blk >> 7, h = (blk >> 1) & 63, wh = blk & 1;
    const int w0 = wh * 32;
    const int t = threadIdx.x;
    const int wid = t >> 6, lane = t & 63;
    const int l31 = lane & 31, lhi = lane >> 5;
    const int cg = t & 7, nl = (t >> 3) & 63;

    __shared__ __align__(16) int4 s_meta[GK * 64];          // 36864 B
    __shared__ __align__(16) _Float16 sB[2][2][64 * 64];    // 32768 B
    __shared__ float s_shp[2 * 4 * 32];                     //  1024 B
    __shared__ float s_woff[GK * 8];                        //  1152 B

    // ---- stage shp slice + all 288 w_off ----
    if (t < 256) {
        int bb = t >> 7, c = (t >> 5) & 3, wl = t & 31;
        s_shp[t] = shp[(((bp * 2 + bb) * 4 + c) << 12) + h * Wn + w0 + wl];
    }
    for (int u = t; u < GK * 8; u += 512) s_woff[u] = w_off[u];
    __syncthreads();

    // ---- meta: one 16B record per (gk, n): {lin01, lin23, alpha f16x4} ----
    for (int i = t; i < GK * 64; i += 512) {
        int gk = i >> 6, n = i & 63;
        int bb = n >> 5, wl = n & 31;
        int g = gk / Kn, k = gk - g * Kn;
        int ky = k / 3, kx = k - ky * 3;
        float dy = 0.f, dx = 0.f;
#pragma unroll
        for (int c = 0; c < 4; c++) {
            float sv = s_shp[(bb * 4 + c) * 32 + wl];
            dy = fmaf(s_woff[gk * 8 + c],     sv, dy);
            dx = fmaf(s_woff[gk * 8 + 4 + c], sv, dx);
        }
        float py = (float)(h + ky - 1) + dy;
        float px = (float)(w0 + wl + kx - 1) + dx;
        float y0 = floorf(py), x0 = floorf(px);
        float fy = py - y0, fx = px - x0;
        int iy = (int)y0, ix = (int)x0;
        bool y0v = (unsigned)iy       < (unsigned)Hn;
        bool y1v = (unsigned)(iy + 1) < (unsigned)Hn;
        bool x0v = (unsigned)ix       < (unsigned)Wn;
        bool x1v = (unsigned)(ix + 1) < (unsigned)Wn;
        int yc0 = min(max(iy, 0), Hn - 1), yc1 = min(max(iy + 1, 0), Hn - 1);
        int xc0 = min(max(ix, 0), Wn - 1), xc1 = min(max(ix + 1, 0), Wn - 1);
        int l00 = yc0 * Wn + xc0, l01 = yc0 * Wn + xc1;
        int l10 = yc1 * Wn + xc0, l11 = yc1 * Wn + xc1;
        float wy1 = fy, wy0 = 1.f - fy, wx1 = fx, wx0 = 1.f - fx;
        float w00 = (y0v && x0v) ? wy0 * wx0 : 0.f;
        float w01 = (y0v && x1v) ? wy0 * wx1 : 0.f;
        float w10 = (y1v && x0v) ? wy1 * wx0 : 0.f;
        float w11 = (y1v && x1v) ? wy1 * wx1 : 0.f;
        f16x2 p0, p1;
        p0.x = (_Float16)w00; p0.y = (_Float16)w01;
        p1.x = (_Float16)w10; p1.y = (_Float16)w11;
        s_meta[i] = make_int4(l00 | (l01 << 16), l10 | (l11 << 16),
                              __builtin_bit_cast(int, p0),
                              __builtin_bit_cast(int, p1));
    }

    // ONE corner slot: pair granularity, g2 index always compile-time.
    f16x8 c4[2][4];
    int2  amv[2];

    auto issue = [&](int p) {               // corners for gk pair p -> c4
#pragma unroll
        for (int g2 = 0; g2 < 2; g2++) {
            int gk = p * 2 + g2;
            int4 mv = s_meta[gk * 64 + nl];
            amv[g2].x = mv.z; amv[g2].y = mv.w;
            int b = bp * 2 + (nl >> 5);
            int g = gk / Kn;
            const _Float16* base = xt + (((size_t)b << 12)) * 256 + g * CPG + cg * 8;
            c4[g2][0] = *(const f16x8*)(base + (size_t)(mv.x & 0xffff) * 256);
            c4[g2][1] = *(const f16x8*)(base + (size_t)((unsigned)mv.x >> 16) * 256);
            c4[g2][2] = *(const f16x8*)(base + (size_t)(mv.y & 0xffff) * 256);
            c4[g2][3] = *(const f16x8*)(base + (size_t)((unsigned)mv.y >> 16) * 256);
        }
    };
    auto commit = [&](int buf) {            // interp c4 -> sB[buf][0..1]
#pragma unroll
        for (int g2 = 0; g2 < 2; g2++) {
            f16x2 h0 = __builtin_bit_cast(f16x2, amv[g2].x);
            f16x2 h1 = __builtin_bit_cast(f16x2, amv[g2].y);
            f16x2 a00; a00.x = h0.x; a00.y = h0.x;
            f16x2 a01; a01.x = h0.y; a01.y = h0.y;
            f16x2 a10; a10.x = h1.x; a10.y = h1.x;
            f16x2 a11; a11.x = h1.y; a11.y = h1.y;
            int4 rp;
#pragma unroll
            for (int r = 0; r < 4; r++) {
                f16x2 s = a00 * pair_of(c4[g2][0], r);
                s = a01 * pair_of(c4[g2][1], r) + s;
                s = a10 * pair_of(c4[g2][2], r) + s;
                s = a11 * pair_of(c4[g2][3], r) + s;
                int sv = __builtin_bit_cast(int, s);
                if (r == 0) rp.x = sv; else if (r == 1) rp.y = sv;
                else if (r == 2) rp.z = sv; else rp.w = sv;
            }
            *(int4*)&sB[buf][g2][(nl * 8 + (cg ^ (nl & 7))) * 8] = rp;
        }
    };

    f32x16 acc[2];
#pragma unroll
    for (int nt = 0; nt < 2; nt++)
#pragma unroll
        for (int r = 0; r < 16; r++) acc[nt][r] = 0.f;

    __syncthreads();            // meta visible

    issue(0);
    commit(0);                  // sB[0] = tiles of pair 0
    issue(1);                   // corners(pair 1) in c4
    BAR_LDS();

    for (int p = 0; p < NP; p++) {
        const int buf = p & 1;
        // 1) A-frags for THIS pair (8 loads, oldest vm -> MFMA's wait leaves
        //    the corner gathers below in flight)
        f16x8 af[8];
#pragma unroll
        for (int g2 = 0; g2 < 2; g2++) {
            const _Float16* wbase = wfrag + (((size_t)(p * 2 + g2) * 8 + wid) * 4) * 512;
#pragma unroll
            for (int ks = 0; ks < 4; ks++)
                af[g2 * 4 + ks] = *(const f16x8*)(wbase + ((size_t)ks * 64 + lane) * 8);
        }
        // 2) interp pair p+1 (corners landed last iter) -> other buffer
        if (p + 1 < NP) commit(buf ^ 1);
        // 3) corner loads for pair p+2 (c4 freed by the commit above)
        if (p + 2 < NP) issue(p + 2);
        // 4) MFMA on buf: 8 K-steps (2 tiles x 4 ks) x 2 n-tiles
#pragma unroll
        for (int ks8 = 0; ks8 < 8; ks8++) {
            int tile = ks8 >> 2;
            int cb = (ks8 & 3) * 2 + lhi;
#pragma unroll
            for (int nt = 0; nt < 2; nt++) {
                int n = nt * 32 + l31;
                f16x8 bf = *(const f16x8*)&sB[buf][tile][(n * 8 + (cb ^ (n & 7))) * 8];
                acc[nt] = __builtin_amdgcn_mfma_f32_32x32x16_f16(
                    af[ks8], bf, acc[nt], 0, 0, 0);
            }
        }
        BAR_LDS();              // LDS-only barrier: no vmcnt drain
    }

    // ---- epilogue: C/D 32x32: col=lane&31, row=(reg&3)+8*(reg>>2)+4*lhi ----
#pragma unroll
    for (int nt = 0; nt < 2; nt++) {
        int b = bp * 2 + nt;
        float* op = out + ((size_t)b * COUT << 12) + h * Wn + w0 + l31;
#pragma unroll
        for (int reg = 0; reg < 16; reg++) {
            int row = (reg & 3) + 8 * (reg >> 2) + 4 * lhi;
            int o = wid * 32 + row;
            op[(size_t)o << 12] = fmaxf(acc[nt][reg], 0.f);
        }
    }
}

// ---------------------------------------------------------------------------
extern "C" void kernel_launch(void* const* d_in, const int* in_sizes, int n_in,
                              void* d_out, int out_size, void* d_ws, size_t ws_size,
                              hipStream_t stream) {
    const float* x     = (const float*)d_in[0];
    const float* shp   = (const float*)d_in[1];
    const float* w_off = (const float*)d_in[2];
    const float* w_def = (const float*)d_in[3];
    float* out = (float*)d_out;
    _Float16* wfrag = (_Float16*)d_ws;                         // 1.18 MB
    _Float16* xt    = (_Float16*)((char*)d_ws + (2u << 20));   // 16.8 MB

    fa_prep<<<4096 + 32, 256, 0, stream>>>(x, w_def, xt, wfrag);
    fa_main<<<512, 512, 0, stream>>>(xt, shp, w_off, wfrag, out);
}